// Round 1
// baseline (5303.402 us; speedup 1.0000x reference)
//
#include <hip/hip_runtime.h>
#include <hip/hip_bf16.h>
#include <cstdint>
#include <cstddef>

#define HD 768   // H == H2
#define GD 2304  // 3*H2 (gate dim)
#define DD 1536  // 2*H2 (bigru out dim)

// ---------------- workspace layout (float offsets) ----------------
// total = 60,342,272 floats = 241.4 MB
static constexpr size_t SZ_XP_TW   = (size_t)8192 * GD;   // 18,874,368
static constexpr size_t SZ_XP_TP   = (size_t)1024 * GD;   //  2,359,296
static constexpr size_t OFF_XP_TWF = 0;
static constexpr size_t OFF_XP_TWB = OFF_XP_TWF + SZ_XP_TW;
static constexpr size_t OFF_XP_TPF = OFF_XP_TWB + SZ_XP_TW;
static constexpr size_t OFF_XP_TPB = OFF_XP_TPF + SZ_XP_TP;
static constexpr size_t OFF_TW     = OFF_XP_TPB + SZ_XP_TP;            // 8192*1536
static constexpr size_t OFF_TP     = OFF_TW + (size_t)8192 * DD;       // 1024*1536
static constexpr size_t OFF_H0     = OFF_TP + (size_t)1024 * DD;       // 288*768
static constexpr size_t OFF_H1     = OFF_H0 + (size_t)288 * HD;
static constexpr size_t OFF_TPW    = OFF_H1 + (size_t)288 * HD;        // 1024*1536
static constexpr size_t OFF_S      = OFF_TPW + (size_t)1024 * DD;      // 64*16*128
static constexpr size_t OFF_R     = OFF_S + (size_t)64 * 16 * 128;     // 1024*1536

__device__ __forceinline__ float sigmoidf_(float x) { return 1.f / (1.f + expf(-x)); }

// ---------------- zero-init (ws is poisoned 0xAA before every call) ----------------
__global__ void zero_kernel(float* __restrict__ p, int n) {
  int i = blockIdx.x * 256 + threadIdx.x;
  if (i < n) p[i] = 0.f;
}

// ---------------- xp GEMM: out[M x 2304] = emb[ids][M x 768] @ W^T + bias ----------------
// tile 128x128, BK=16, 256 threads, 8x8 microtile (split 4+4 to avoid 4-way LDS conflicts)
__global__ __launch_bounds__(256) void xp_gemm_kernel(
    const int* __restrict__ ids, const float* __restrict__ emb,
    const float* __restrict__ W, const float* __restrict__ bias,
    float* __restrict__ out)
{
  __shared__ float As[16][128];
  __shared__ float Bs[16][128];
  const int tid   = threadIdx.x;
  const int mBase = blockIdx.y << 7;
  const int nBase = blockIdx.x << 7;
  const int lr = tid >> 2;          // 0..63
  const int lk = (tid & 3) << 2;    // 0,4,8,12
  const int r0 = ids[mBase + lr];
  const int r1 = ids[mBase + 64 + lr];
  const float* pa0 = emb + (size_t)r0 * HD + lk;
  const float* pa1 = emb + (size_t)r1 * HD + lk;
  const float* pb0 = W + (size_t)(nBase + lr) * HD + lk;
  const float* pb1 = W + (size_t)(nBase + 64 + lr) * HD + lk;
  const int tm = tid >> 4;          // 0..15
  const int tn = tid & 15;

  float acc[8][8];
#pragma unroll
  for (int i = 0; i < 8; ++i)
#pragma unroll
    for (int j = 0; j < 8; ++j) acc[i][j] = 0.f;

  for (int k0 = 0; k0 < HD; k0 += 16) {
    const float4 va0 = *(const float4*)(pa0 + k0);
    const float4 va1 = *(const float4*)(pa1 + k0);
    const float4 vb0 = *(const float4*)(pb0 + k0);
    const float4 vb1 = *(const float4*)(pb1 + k0);
    __syncthreads();
    As[lk+0][lr] = va0.x; As[lk+1][lr] = va0.y; As[lk+2][lr] = va0.z; As[lk+3][lr] = va0.w;
    As[lk+0][64+lr] = va1.x; As[lk+1][64+lr] = va1.y; As[lk+2][64+lr] = va1.z; As[lk+3][64+lr] = va1.w;
    Bs[lk+0][lr] = vb0.x; Bs[lk+1][lr] = vb0.y; Bs[lk+2][lr] = vb0.z; Bs[lk+3][lr] = vb0.w;
    Bs[lk+0][64+lr] = vb1.x; Bs[lk+1][64+lr] = vb1.y; Bs[lk+2][64+lr] = vb1.z; Bs[lk+3][64+lr] = vb1.w;
    __syncthreads();
#pragma unroll
    for (int kk = 0; kk < 16; ++kk) {
      float a[8], b[8];
      *(float4*)&a[0] = *(const float4*)&As[kk][tm<<2];
      *(float4*)&a[4] = *(const float4*)&As[kk][64 + (tm<<2)];
      *(float4*)&b[0] = *(const float4*)&Bs[kk][tn<<2];
      *(float4*)&b[4] = *(const float4*)&Bs[kk][64 + (tn<<2)];
#pragma unroll
      for (int i = 0; i < 8; ++i)
#pragma unroll
        for (int j = 0; j < 8; ++j) acc[i][j] += a[i] * b[j];
    }
  }

#pragma unroll
  for (int i = 0; i < 8; ++i) {
    const int row = mBase + ((i < 4) ? ((tm<<2) + i) : (64 + (tm<<2) + (i - 4)));
    float* po = out + (size_t)row * GD + nBase;
#pragma unroll
    for (int jh = 0; jh < 2; ++jh) {
      const int co = (jh << 6) + (tn << 2);
      float4 v;
      v.x = acc[i][jh*4+0] + bias[nBase + co + 0];
      v.y = acc[i][jh*4+1] + bias[nBase + co + 1];
      v.z = acc[i][jh*4+2] + bias[nBase + co + 2];
      v.w = acc[i][jh*4+3] + bias[nBase + co + 3];
      *(float4*)(po + co) = v;
    }
  }
}

// ---------------- one GRU step for all 4 recurrences ----------------
// combined H rows: [0,128) tweet-fwd, [128,256) tweet-bwd, [256,272) topic-fwd, [272,288) topic-bwd
// grid: x = j-tile (12 x 64 cols), y = M-tile (18 x 16 rows); block 256
__global__ __launch_bounds__(256) void gru_step_kernel(
    const float* __restrict__ Whh_f, const float* __restrict__ Whh_b,
    const float* __restrict__ bhh_f, const float* __restrict__ bhh_b,
    const float* __restrict__ xp_twf, const float* __restrict__ xp_twb,
    const float* __restrict__ xp_tpf, const float* __restrict__ xp_tpb,
    const float* __restrict__ Hprev, float* __restrict__ Hnext,
    float* __restrict__ TW, float* __restrict__ TP, const int s)
{
  __shared__ float Hs[16][16];
  __shared__ float Ws[3][16][64];
  const int tid = threadIdx.x;
  const int my  = blockIdx.y;
  const int jBase = blockIdx.x << 6;
  const int rowBase = my << 4;
  const int seg = (my < 8) ? 0 : (my < 16) ? 1 : (my - 14);  // 0 twf, 1 twb, 2 tpf, 3 tpb
  const bool fwd = (seg == 0) || (seg == 2);
  const float* __restrict__ Whh = fwd ? Whh_f : Whh_b;
  const float* __restrict__ bhh = fwd ? bhh_f : bhh_b;

  const int hk = tid & 15, hr = tid >> 4;     // H loader: coalesced along k
  const int wr = tid >> 2;                    // 0..63 (gate col within tile)
  const int wk = (tid & 3) << 2;
  const int row = tid & 15;                   // compute row
  const int cq  = tid >> 4;                   // compute col-quad

  const float* pH  = Hprev + (size_t)(rowBase + hr) * HD + hk;
  const float* pW0 = Whh + (size_t)(          jBase + wr) * HD + wk;
  const float* pW1 = Whh + (size_t)(HD      + jBase + wr) * HD + wk;
  const float* pW2 = Whh + (size_t)(2 * HD  + jBase + wr) * HD + wk;

  float accr[4] = {0.f,0.f,0.f,0.f};
  float accz[4] = {0.f,0.f,0.f,0.f};
  float accn[4] = {0.f,0.f,0.f,0.f};

  for (int k0 = 0; k0 < HD; k0 += 16) {
    const float  hval = pH[k0];
    const float4 w0 = *(const float4*)(pW0 + k0);
    const float4 w1 = *(const float4*)(pW1 + k0);
    const float4 w2 = *(const float4*)(pW2 + k0);
    __syncthreads();
    Hs[hk][hr] = hval;
    Ws[0][wk+0][wr] = w0.x; Ws[0][wk+1][wr] = w0.y; Ws[0][wk+2][wr] = w0.z; Ws[0][wk+3][wr] = w0.w;
    Ws[1][wk+0][wr] = w1.x; Ws[1][wk+1][wr] = w1.y; Ws[1][wk+2][wr] = w1.z; Ws[1][wk+3][wr] = w1.w;
    Ws[2][wk+0][wr] = w2.x; Ws[2][wk+1][wr] = w2.y; Ws[2][wk+2][wr] = w2.z; Ws[2][wk+3][wr] = w2.w;
    __syncthreads();
#pragma unroll
    for (int kk = 0; kk < 16; ++kk) {
      const float  h  = Hs[kk][row];
      const float4 vr = *(const float4*)&Ws[0][kk][cq<<2];
      const float4 vz = *(const float4*)&Ws[1][kk][cq<<2];
      const float4 vn = *(const float4*)&Ws[2][kk][cq<<2];
      accr[0] += h*vr.x; accr[1] += h*vr.y; accr[2] += h*vr.z; accr[3] += h*vr.w;
      accz[0] += h*vz.x; accz[1] += h*vz.y; accz[2] += h*vz.z; accz[3] += h*vz.w;
      accn[0] += h*vn.x; accn[1] += h*vn.y; accn[2] += h*vn.z; accn[3] += h*vn.w;
    }
  }

  const int t = fwd ? s : (63 - s);      // backward consumes xp[63-s], writes hs[63-s]
  const int gRow = rowBase + row;
  const float* xp;
  float* hOut;
  if (seg == 0) {
    const int l = gRow;
    xp   = xp_twf + ((size_t)s * 128 + l) * GD;
    hOut = TW + ((size_t)t * 128 + l) * DD;
  } else if (seg == 1) {
    const int l = gRow - 128;
    xp   = xp_twb + ((size_t)t * 128 + l) * GD;
    hOut = TW + ((size_t)t * 128 + l) * DD + HD;
  } else if (seg == 2) {
    const int l = gRow - 256;
    xp   = xp_tpf + ((size_t)s * 16 + l) * GD;
    hOut = TP + ((size_t)t * 16 + l) * DD;
  } else {
    const int l = gRow - 272;
    xp   = xp_tpb + ((size_t)t * 16 + l) * GD;
    hOut = TP + ((size_t)t * 16 + l) * DD + HD;
  }
  const float* hPrevRow = Hprev + (size_t)gRow * HD;
  float*       hNextRow = Hnext + (size_t)gRow * HD;

#pragma unroll
  for (int c = 0; c < 4; ++c) {
    const int j = jBase + (cq << 2) + c;
    const float xr = xp[j], xz = xp[HD + j], xn = xp[2*HD + j];
    const float gr = accr[c] + bhh[j];
    const float gz = accz[c] + bhh[HD + j];
    const float gn = accn[c] + bhh[2*HD + j];
    const float rg = sigmoidf_(xr + gr);
    const float zg = sigmoidf_(xz + gz);
    const float nn = tanhf(xn + rg * gn);
    const float hp = hPrevRow[j];
    const float hv = (1.f - zg) * nn + zg * hp;
    hNextRow[j] = hv;
    hOut[j]     = hv;
  }
}

// ---------------- TPW = TP(1024x1536) @ W_bl(1536x1536), B is K-major ----------------
// tile 64x128, BK=16, 256 threads, 4x8 microtile
__global__ __launch_bounds__(256) void tpw_gemm_kernel(
    const float* __restrict__ TPm, const float* __restrict__ Wbl, float* __restrict__ TPW)
{
  __shared__ float As[16][64];
  __shared__ float Bs[16][128];
  const int tid = threadIdx.x;
  const int mBase = blockIdx.y << 6;
  const int nBase = blockIdx.x << 7;
  const int ar = tid >> 2, ak = (tid & 3) << 2;
  const int bk = tid >> 4, bn = (tid & 15) << 3;
  const float* pa = TPm + (size_t)(mBase + ar) * DD + ak;
  const float* pb = Wbl + (size_t)bk * DD + nBase + bn;
  const int tm = tid >> 4, tn = tid & 15;
  float acc[4][8];
#pragma unroll
  for (int i = 0; i < 4; ++i)
#pragma unroll
    for (int j = 0; j < 8; ++j) acc[i][j] = 0.f;

  for (int k0 = 0; k0 < DD; k0 += 16) {
    const float4 va  = *(const float4*)(pa + k0);
    const float4 vb0 = *(const float4*)(pb + (size_t)k0 * DD);
    const float4 vb1 = *(const float4*)(pb + (size_t)k0 * DD + 4);
    __syncthreads();
    As[ak+0][ar] = va.x; As[ak+1][ar] = va.y; As[ak+2][ar] = va.z; As[ak+3][ar] = va.w;
    *(float4*)&Bs[bk][bn]     = vb0;
    *(float4*)&Bs[bk][bn + 4] = vb1;
    __syncthreads();
#pragma unroll
    for (int kk = 0; kk < 16; ++kk) {
      float a[4], b[8];
      *(float4*)&a[0] = *(const float4*)&As[kk][tm<<2];
      *(float4*)&b[0] = *(const float4*)&Bs[kk][tn<<2];
      *(float4*)&b[4] = *(const float4*)&Bs[kk][64 + (tn<<2)];
#pragma unroll
      for (int i = 0; i < 4; ++i)
#pragma unroll
        for (int j = 0; j < 8; ++j) acc[i][j] += a[i] * b[j];
    }
  }

#pragma unroll
  for (int i = 0; i < 4; ++i) {
    float* po = TPW + (size_t)(mBase + (tm<<2) + i) * DD + nBase;
    *(float4*)(po + (tn<<2))      = make_float4(acc[i][0], acc[i][1], acc[i][2], acc[i][3]);
    *(float4*)(po + 64 + (tn<<2)) = make_float4(acc[i][4], acc[i][5], acc[i][6], acc[i][7]);
  }
}

// ---------------- S[b,t,l] = sum_d TPW[b,t,d] * TW[b,l,d] ----------------
__global__ __launch_bounds__(128) void s_kernel(
    const float* __restrict__ TPW, const float* __restrict__ TW, float* __restrict__ S)
{
  __shared__ float tp_s[DD];
  const int t = blockIdx.x, b = blockIdx.y, tid = threadIdx.x;
  const float* src = TPW + ((size_t)b * 16 + t) * DD;
  for (int i = tid * 4; i < DD; i += 128 * 4) *(float4*)&tp_s[i] = *(const float4*)&src[i];
  __syncthreads();
  const float* twp = TW + (size_t)(b * 128 + tid) * DD;
  float acc = 0.f;
  for (int d = 0; d < DD; d += 4) {
    const float4 tv = *(const float4*)(twp + d);
    acc += tp_s[d]*tv.x + tp_s[d+1]*tv.y + tp_s[d+2]*tv.z + tp_s[d+3]*tv.w;
  }
  S[((size_t)b * 16 + t) * 128 + tid] = acc;
}

// ---------------- r[b,t,:] = softmax(S[b,t,:]) @ TW[b] ----------------
__global__ __launch_bounds__(256) void r_kernel(
    const float* __restrict__ S, const float* __restrict__ TW, float* __restrict__ Rr)
{
  __shared__ float att[128];
  const int t = blockIdx.x, b = blockIdx.y, tid = threadIdx.x;
  const float* srow = S + ((size_t)b * 16 + t) * 128;
  if (tid < 128) att[tid] = srow[tid];
  __syncthreads();
  float m = -1e30f;
  for (int i = 0; i < 128; ++i) m = fmaxf(m, att[i]);   // broadcast reads, all threads same m
  __syncthreads();
  if (tid < 128) att[tid] = expf(att[tid] - m);
  __syncthreads();
  float ssum = 0.f;
  for (int i = 0; i < 128; ++i) ssum += att[i];
  const float inv = 1.f / ssum;

  float racc[6] = {0.f,0.f,0.f,0.f,0.f,0.f};
  const float* twb = TW + (size_t)b * 128 * DD;
  for (int l = 0; l < 128; ++l) {
    const float a = att[l];
    const float* twl = twb + (size_t)l * DD + tid;
#pragma unroll
    for (int k = 0; k < 6; ++k) racc[k] += a * twl[k * 256];
  }
  float* ro = Rr + ((size_t)b * 16 + t) * DD + tid;
#pragma unroll
  for (int k = 0; k < 6; ++k) ro[k * 256] = racc[k] * inv;
}

// ---------------- R assembly + head: d_out = [out(64x2), R(64x3072)] ----------------
__global__ __launch_bounds__(256) void final_kernel(
    const float* __restrict__ Rr, const float* __restrict__ beta,
    const float* __restrict__ detW, const float* __restrict__ detb,
    float* __restrict__ dout)
{
  __shared__ float bet[16];
  __shared__ float red0[256], red1[256];
  const int b = blockIdx.x, tid = threadIdx.x;
  if (tid < 16) bet[tid] = beta[tid];
  __syncthreads();
  const float* rb = Rr + (size_t)b * 16 * DD;
  float* Rout = dout + 128 + (size_t)b * 3072;
  float p0 = 0.f, p1 = 0.f;
  for (int d = tid; d < 3072; d += 256) {   // branch is uniform per iteration (d<1536 <=> iter<6)
    float v;
    if (d < DD) {
      v = rb[15 * DD + d];                  // r[:, -1]
    } else {
      float sum = 0.f;
#pragma unroll
      for (int tt = 0; tt < 15; ++tt) sum += bet[tt] * rb[(size_t)tt * DD + (d - DD)];
      v = sum;                              // mean_r with beta[:-1]
    }
    Rout[d] = v;
    p0 += v * detW[d];
    p1 += v * detW[3072 + d];
  }
  red0[tid] = p0; red1[tid] = p1;
  __syncthreads();
  for (int off = 128; off > 0; off >>= 1) {
    if (tid < off) { red0[tid] += red0[tid + off]; red1[tid] += red1[tid + off]; }
    __syncthreads();
  }
  if (tid == 0) {
    dout[b * 2 + 0] = red0[0] + detb[0];
    dout[b * 2 + 1] = red1[0] + detb[1];
  }
}

// ---------------- launch ----------------
extern "C" void kernel_launch(void* const* d_in, const int* in_sizes, int n_in,
                              void* d_out, int out_size, void* d_ws, size_t ws_size,
                              hipStream_t stream)
{
  (void)in_sizes; (void)n_in; (void)out_size; (void)ws_size;
  const int*   tweet = (const int*)  d_in[0];
  const int*   topic = (const int*)  d_in[1];
  const float* beta  = (const float*)d_in[2];
  const float* emb   = (const float*)d_in[3];
  const float* Wih_f = (const float*)d_in[4];
  const float* Whh_f = (const float*)d_in[5];
  const float* bih_f = (const float*)d_in[6];
  const float* bhh_f = (const float*)d_in[7];
  const float* Wih_b = (const float*)d_in[8];
  const float* Whh_b = (const float*)d_in[9];
  const float* bih_b = (const float*)d_in[10];
  const float* bhh_b = (const float*)d_in[11];
  const float* W_bl  = (const float*)d_in[12];
  const float* det_W = (const float*)d_in[13];
  const float* det_b = (const float*)d_in[14];

  float* ws     = (float*)d_ws;
  float* xp_twf = ws + OFF_XP_TWF;
  float* xp_twb = ws + OFF_XP_TWB;
  float* xp_tpf = ws + OFF_XP_TPF;
  float* xp_tpb = ws + OFF_XP_TPB;
  float* TW     = ws + OFF_TW;
  float* TPm    = ws + OFF_TP;
  float* H0     = ws + OFF_H0;
  float* H1     = ws + OFF_H1;
  float* TPW    = ws + OFF_TPW;
  float* Sb     = ws + OFF_S;
  float* Rr     = ws + OFF_R;

  // h0 = 0 for all 4 recurrences (ws is poisoned before each timed call)
  zero_kernel<<<dim3((288 * HD + 255) / 256), dim3(256), 0, stream>>>(H0, 288 * HD);

  // xp = emb[ids] @ Wih^T + bih   (4 independent GEMMs)
  xp_gemm_kernel<<<dim3(18, 64), dim3(256), 0, stream>>>(tweet, emb, Wih_f, bih_f, xp_twf);
  xp_gemm_kernel<<<dim3(18, 64), dim3(256), 0, stream>>>(tweet, emb, Wih_b, bih_b, xp_twb);
  xp_gemm_kernel<<<dim3(18, 8),  dim3(256), 0, stream>>>(topic, emb, Wih_f, bih_f, xp_tpf);
  xp_gemm_kernel<<<dim3(18, 8),  dim3(256), 0, stream>>>(topic, emb, Wih_b, bih_b, xp_tpb);

  // 64 sequential GRU steps (scan over leading axis), ping-pong H buffers
  for (int s = 0; s < 64; ++s) {
    const float* hp = (s & 1) ? H1 : H0;
    float*       hn = (s & 1) ? H0 : H1;
    gru_step_kernel<<<dim3(12, 18), dim3(256), 0, stream>>>(
        Whh_f, Whh_b, bhh_f, bhh_b, xp_twf, xp_twb, xp_tpf, xp_tpb,
        hp, hn, TW, TPm, s);
  }

  // attention + head
  tpw_gemm_kernel<<<dim3(12, 16), dim3(256), 0, stream>>>(TPm, W_bl, TPW);
  s_kernel<<<dim3(16, 64), dim3(128), 0, stream>>>(TPW, TW, Sb);
  r_kernel<<<dim3(16, 64), dim3(256), 0, stream>>>(Sb, TW, Rr);
  final_kernel<<<dim3(64), dim3(256), 0, stream>>>(Rr, beta, det_W, det_b, (float*)d_out);
}

// Round 2
// 2125.086 us; speedup vs baseline: 2.4956x; 2.4956x over previous
//
#include <hip/hip_runtime.h>
#include <hip/hip_bf16.h>
#include <cstdint>
#include <cstddef>

#define HD 768   // H == H2
#define GD 2304  // 3*H2
#define DD 1536  // 2*H2

typedef __attribute__((ext_vector_type(8))) short bfrag8;  // 8 bf16 (4 VGPRs)
typedef __attribute__((ext_vector_type(4))) float f32x4;   // MFMA acc

// ---------------- workspace layout (float offsets) ----------------
// region xp (live: xp-gemm .. gru; overlaid by attention bufs afterwards)
static constexpr size_t F_XP_TWF = 0;                      // 8192*2304
static constexpr size_t F_XP_TWB = 18874368;               // 8192*2304
static constexpr size_t F_XP_TPF = 37748736;               // 1024*2304
static constexpr size_t F_XP_TPB = 40108032;               // 1024*2304
// attention overlay (phase 4) inside xp region:
static constexpr size_t F_TPW   = 0;                       // 1024*1536
static constexpr size_t F_S     = 1572864;                 // 64*16*128
static constexpr size_t F_R     = 1703936;                 // 1024*1536
// region B: phase1-2 = bf16 splits of X and Wih; phase3-4 = TW/TP (fp32)
static constexpr size_t F_B     = 42467328;
static constexpr size_t U_XTW_HI  = 0;          // ushort offsets within region B
static constexpr size_t U_XTW_LO  = 6291456;
static constexpr size_t U_XTP_HI  = 12582912;
static constexpr size_t U_XTP_LO  = 13369344;
static constexpr size_t U_WIHF_HI = 14155776;
static constexpr size_t U_WIHF_LO = 15925248;
static constexpr size_t U_WIHB_HI = 17694720;
static constexpr size_t U_WIHB_LO = 19464192;
static constexpr size_t F_TW    = F_B;                     // 8192*1536
static constexpr size_t F_TP    = F_B + 12582912;          // 1024*1536
// region Whh splits (ushort), live phase1-3
static constexpr size_t F_WHH   = F_B + 14155776;          // 4 x 1,769,472 ushort
static constexpr size_t U_WHHF_HI = 0;
static constexpr size_t U_WHHF_LO = 1769472;
static constexpr size_t U_WHHB_HI = 3538944;
static constexpr size_t U_WHHB_LO = 5308416;
// H state: bf16 hi/lo ping-pong pairs
static constexpr size_t F_H     = F_WHH + 3538944;
static constexpr size_t U_HPAIR = 442368;   // ushort stride between pair0 and pair1
static constexpr size_t U_HLO   = 221184;   // lo offset within a pair

__device__ __forceinline__ float sigmoidf_(float x) { return 1.f / (1.f + expf(-x)); }

__device__ __forceinline__ unsigned short f2bf(float f) {
  unsigned int u = __builtin_bit_cast(unsigned int, f);
  unsigned int r = (u + 0x7fffu + ((u >> 16) & 1u)) >> 16;
  return (unsigned short)r;
}
__device__ __forceinline__ float bf2f(unsigned short h) {
  unsigned int u = ((unsigned int)h) << 16;
  return __builtin_bit_cast(float, u);
}
__device__ __forceinline__ void glds16(const unsigned short* src, unsigned short* ldsDst) {
  __builtin_amdgcn_global_load_lds((const void*)src, (void*)ldsDst, 16, 0, 0);
}

// ---------------- zero-init ----------------
__global__ void zero_kernel(float* __restrict__ p, int n) {
  int i = blockIdx.x * 256 + threadIdx.x;
  if (i < n) p[i] = 0.f;
}

// ---------------- gather + bf16 hi/lo split: X = emb[ids] ----------------
__global__ __launch_bounds__(256) void gather_split_kernel(
    const int* __restrict__ ids, const float* __restrict__ emb,
    unsigned short* __restrict__ hi, unsigned short* __restrict__ lo, int total4)
{
  int i = blockIdx.x * 256 + threadIdx.x;
  if (i >= total4) return;
  int r = i / 192;                  // 192 float4 per 768-row
  int c = (i - r * 192) * 4;
  const float4 v = *reinterpret_cast<const float4*>(emb + (size_t)ids[r] * HD + c);
  float vv[4] = {v.x, v.y, v.z, v.w};
  unsigned int ph0, ph1, pl0, pl1;
  unsigned short h[4], l[4];
#pragma unroll
  for (int e = 0; e < 4; ++e) { h[e] = f2bf(vv[e]); l[e] = f2bf(vv[e] - bf2f(h[e])); }
  ph0 = (unsigned int)h[0] | ((unsigned int)h[1] << 16);
  ph1 = (unsigned int)h[2] | ((unsigned int)h[3] << 16);
  pl0 = (unsigned int)l[0] | ((unsigned int)l[1] << 16);
  pl1 = (unsigned int)l[2] | ((unsigned int)l[3] << 16);
  size_t base = (size_t)i * 4;
  *reinterpret_cast<uint2*>(hi + base) = make_uint2(ph0, ph1);
  *reinterpret_cast<uint2*>(lo + base) = make_uint2(pl0, pl1);
}

// ---------------- bf16 hi/lo split of a weight matrix ----------------
__global__ __launch_bounds__(256) void split_w_kernel(
    const float* __restrict__ src, unsigned short* __restrict__ hi,
    unsigned short* __restrict__ lo, int total4)
{
  int i = blockIdx.x * 256 + threadIdx.x;
  if (i >= total4) return;
  const float4 v = *reinterpret_cast<const float4*>(src + (size_t)i * 4);
  float vv[4] = {v.x, v.y, v.z, v.w};
  unsigned short h[4], l[4];
#pragma unroll
  for (int e = 0; e < 4; ++e) { h[e] = f2bf(vv[e]); l[e] = f2bf(vv[e] - bf2f(h[e])); }
  unsigned int ph0 = (unsigned int)h[0] | ((unsigned int)h[1] << 16);
  unsigned int ph1 = (unsigned int)h[2] | ((unsigned int)h[3] << 16);
  unsigned int pl0 = (unsigned int)l[0] | ((unsigned int)l[1] << 16);
  unsigned int pl1 = (unsigned int)l[2] | ((unsigned int)l[3] << 16);
  size_t base = (size_t)i * 4;
  *reinterpret_cast<uint2*>(hi + base) = make_uint2(ph0, ph1);
  *reinterpret_cast<uint2*>(lo + base) = make_uint2(pl0, pl1);
}

// ---------------- xp GEMM, bf16x3 MFMA ----------------
// out[M x 2304] = X[M x 768] @ W[2304 x 768]^T + bias, via
// C = Xhi Whi^T + Xlo Whi^T + Xhi Wlo^T   (K' = 3*768)
// BM=BN=128, BK=32. 256 thr = 4 waves (2x2), wave = 64x64 = 4x4 frags of 16x16x32.
// LDS tiles [128 rows][32 bf16] (64B rows), XOR-swizzled: byte ^= (row&3)<<4.
__global__ __launch_bounds__(256, 3) void xp_mfma_kernel(
    const unsigned short* __restrict__ Ahi, const unsigned short* __restrict__ Alo,
    const unsigned short* __restrict__ Bhi, const unsigned short* __restrict__ Blo,
    const float* __restrict__ bias, float* __restrict__ out, int mgc)
{
  __shared__ __align__(16) unsigned short sm[6][4096];  // {B, Ahi, Alo} x dbuf, 8KB each
  const int b = blockIdx.x, nb = gridDim.x;
  const int id = (b & 7) * (nb >> 3) + (b >> 3);        // XCD-sticky colgroups
  const int cg = id / mgc, mg = id % mgc;
  const size_t mBase = (size_t)mg * 128, nBase = (size_t)cg * 128;
  const int tid = threadIdx.x, lane = tid & 63, w = tid >> 6;
  const int wr = w >> 1, wc = w & 1;

  const unsigned short* Ah = Ahi + mBase * HD;
  const unsigned short* Al = Alo + mBase * HD;
  const unsigned short* Bh = Bhi + nBase * HD;
  const unsigned short* Bl = Blo + nBase * HD;

  f32x4 acc[4][4];
#pragma unroll
  for (int i = 0; i < 4; ++i)
#pragma unroll
    for (int j = 0; j < 4; ++j) acc[i][j] = (f32x4){0.f, 0.f, 0.f, 0.f};

  // stage: each wave does instrs {2w, 2w+1} of each 8-instr (8KB) tile
  auto stageF = [&](int buf, int koff) {
    unsigned short* Bt  = sm[buf * 3 + 0];
    unsigned short* At0 = sm[buf * 3 + 1];
    unsigned short* At1 = sm[buf * 3 + 2];
#pragma unroll
    for (int ii = 0; ii < 2; ++ii) {
      int i16 = w * 2 + ii;
      int row = i16 * 16 + (lane >> 2), c16 = lane & 3;
      size_t so = (size_t)row * HD + (size_t)(koff + ((c16 ^ (row & 3)) << 3));
      glds16(Bh + so, Bt + i16 * 512);
      glds16(Ah + so, At0 + i16 * 512);
      glds16(Al + so, At1 + i16 * 512);
    }
  };
  auto stageP = [&](int buf, int koff) {
    unsigned short* Bt  = sm[buf * 3 + 0];
    unsigned short* At0 = sm[buf * 3 + 1];
#pragma unroll
    for (int ii = 0; ii < 2; ++ii) {
      int i16 = w * 2 + ii;
      int row = i16 * 16 + (lane >> 2), c16 = lane & 3;
      size_t so = (size_t)row * HD + (size_t)(koff + ((c16 ^ (row & 3)) << 3));
      glds16(Bl + so, Bt + i16 * 512);
      glds16(Ah + so, At0 + i16 * 512);
    }
  };
  const int kch = (lane >> 4) << 4;

  auto compute = [&](int buf, bool both) {
    const char* Bt  = reinterpret_cast<const char*>(sm[buf * 3 + 0]);
    const char* At0 = reinterpret_cast<const char*>(sm[buf * 3 + 1]);
    const char* At1 = reinterpret_cast<const char*>(sm[buf * 3 + 2]);
    bfrag8 bF[4], aF[4];
#pragma unroll
    for (int j = 0; j < 4; ++j) {
      int row = wc * 64 + j * 16 + (lane & 15);
      bF[j] = *reinterpret_cast<const bfrag8*>(Bt + row * 64 + (kch ^ ((row & 3) << 4)));
    }
#pragma unroll
    for (int i = 0; i < 4; ++i) {
      int row = wr * 64 + i * 16 + (lane & 15);
      aF[i] = *reinterpret_cast<const bfrag8*>(At0 + row * 64 + (kch ^ ((row & 3) << 4)));
    }
#pragma unroll
    for (int i = 0; i < 4; ++i)
#pragma unroll
      for (int j = 0; j < 4; ++j)
        acc[i][j] = __builtin_amdgcn_mfma_f32_16x16x32_bf16(aF[i], bF[j], acc[i][j], 0, 0, 0);
    if (both) {
#pragma unroll
      for (int i = 0; i < 4; ++i) {
        int row = wr * 64 + i * 16 + (lane & 15);
        aF[i] = *reinterpret_cast<const bfrag8*>(At1 + row * 64 + (kch ^ ((row & 3) << 4)));
      }
#pragma unroll
      for (int i = 0; i < 4; ++i)
#pragma unroll
        for (int j = 0; j < 4; ++j)
          acc[i][j] = __builtin_amdgcn_mfma_f32_16x16x32_bf16(aF[i], bF[j], acc[i][j], 0, 0, 0);
    }
  };

  stageF(0, 0);
  __syncthreads();
  for (int kb = 0; kb < 24; ++kb) {            // B=Whi with A=hi,lo
    if (kb < 23) stageF((kb + 1) & 1, (kb + 1) * 32);
    else         stageP(0, 0);
    compute(kb & 1, true);
    __syncthreads();
  }
  for (int kb = 0; kb < 24; ++kb) {            // B=Wlo with A=hi
    if (kb < 23) stageP((kb + 1) & 1, (kb + 1) * 32);
    compute(kb & 1, false);
    __syncthreads();
  }

#pragma unroll
  for (int i = 0; i < 4; ++i)
#pragma unroll
    for (int j = 0; j < 4; ++j) {
      int col = (int)nBase + wc * 64 + j * 16 + (lane & 15);
      float bsv = bias[col];
#pragma unroll
      for (int p = 0; p < 4; ++p) {
        size_t row = mBase + wr * 64 + i * 16 + ((lane >> 4) << 2) + p;
        out[row * GD + col] = acc[i][j][p] + bsv;
      }
    }
}

// ---------------- GRU step, bf16x3 MFMA ----------------
// Rows 0..143 fwd (128 twf + 16 tpf), 144..287 bwd (128 twb + 16 tpb).
// Grid 216 = 12 colgroups(64 h-cols) x 18 rowgroups(16 rows). 4 waves; wave w
// owns h-cols [j0+16w, +16) for all 3 gates: 3 MFMA frags, acc[3].
// B LDS tile [192 rows=g*64+w*16+c][32 bf16], A tile [16][32], XOR-swizzled.
__global__ __launch_bounds__(256) void gru_mfma_kernel(
    const unsigned short* __restrict__ WfHi, const unsigned short* __restrict__ WfLo,
    const unsigned short* __restrict__ WbHi, const unsigned short* __restrict__ WbLo,
    const float* __restrict__ bhhF, const float* __restrict__ bhhB,
    const float* __restrict__ xpTwf, const float* __restrict__ xpTwb,
    const float* __restrict__ xpTpf, const float* __restrict__ xpTpb,
    const unsigned short* __restrict__ Hc, unsigned short* __restrict__ Hn,
    float* __restrict__ TW, float* __restrict__ TP, const int s)
{
  __shared__ __align__(16) unsigned short sm[2][7168];  // B 6144 + Ahi 512 + Alo 512
  const int b = blockIdx.x;
  const int id = (b & 7) * 27 + (b >> 3);
  const int cg = id / 18, rg = id % 18;
  const int rBase = rg * 16, j0 = cg * 64;
  const int dir = rg >= 9;
  const unsigned short* Whi = dir ? WbHi : WfHi;
  const unsigned short* Wlo = dir ? WbLo : WfLo;
  const float* bhh = dir ? bhhB : bhhF;
  const int tid = threadIdx.x, lane = tid & 63, w = tid >> 6;

  f32x4 acc[3];
#pragma unroll
  for (int g = 0; g < 3; ++g) acc[g] = (f32x4){0.f, 0.f, 0.f, 0.f};

  auto stageB = [&](unsigned short* Bt, const unsigned short* Wsrc, int koff) {
#pragma unroll
    for (int ii = 0; ii < 3; ++ii) {
      int i16 = w * 3 + ii;                       // 0..11
      int rr = i16 * 16 + (lane >> 2), c16 = lane & 3;
      size_t wrow = (size_t)(rr >> 6) * HD + j0 + (rr & 63);
      glds16(Wsrc + wrow * HD + (size_t)(koff + ((c16 ^ (rr & 3)) << 3)), Bt + i16 * 512);
    }
  };
  auto stageA = [&](unsigned short* At, const unsigned short* Hsrc, int koff) {
    int row = lane >> 2, c16 = lane & 3;
    glds16(Hsrc + (size_t)(rBase + row) * HD + (size_t)(koff + ((c16 ^ (row & 3)) << 3)), At);
  };
  const unsigned short* HcHi = Hc;
  const unsigned short* HcLo = Hc + U_HLO;
  const int kch = (lane >> 4) << 4;

  auto computeT = [&](int buf, bool both) {
    const char* Bt  = reinterpret_cast<const char*>(sm[buf]);
    const char* At0 = reinterpret_cast<const char*>(sm[buf] + 6144);
    const char* At1 = reinterpret_cast<const char*>(sm[buf] + 6656);
    bfrag8 bF[3];
#pragma unroll
    for (int g = 0; g < 3; ++g) {
      int rr = g * 64 + w * 16 + (lane & 15);
      bF[g] = *reinterpret_cast<const bfrag8*>(Bt + rr * 64 + (kch ^ ((rr & 3) << 4)));
    }
    int arow = lane & 15;
    bfrag8 aF = *reinterpret_cast<const bfrag8*>(At0 + arow * 64 + (kch ^ ((arow & 3) << 4)));
#pragma unroll
    for (int g = 0; g < 3; ++g)
      acc[g] = __builtin_amdgcn_mfma_f32_16x16x32_bf16(aF, bF[g], acc[g], 0, 0, 0);
    if (both) {
      aF = *reinterpret_cast<const bfrag8*>(At1 + arow * 64 + (kch ^ ((arow & 3) << 4)));
#pragma unroll
      for (int g = 0; g < 3; ++g)
        acc[g] = __builtin_amdgcn_mfma_f32_16x16x32_bf16(aF, bF[g], acc[g], 0, 0, 0);
    }
  };

  // prologue stage (fused: B=Whi, A=hi+lo)
  stageB(sm[0], Whi, 0);
  if (w == 0) stageA(sm[0] + 6144, HcHi, 0);
  if (w == 1) stageA(sm[0] + 6656, HcLo, 0);
  __syncthreads();
  for (int kb = 0; kb < 24; ++kb) {
    if (kb < 23) {
      int nb_ = (kb + 1) & 1, ko = (kb + 1) * 32;
      stageB(sm[nb_], Whi, ko);
      if (w == 0) stageA(sm[nb_] + 6144, HcHi, ko);
      if (w == 1) stageA(sm[nb_] + 6656, HcLo, ko);
    } else {
      stageB(sm[0], Wlo, 0);
      if (w == 0) stageA(sm[0] + 6144, HcHi, 0);
    }
    computeT(kb & 1, true);
    __syncthreads();
  }
  for (int kb = 0; kb < 24; ++kb) {            // B=Wlo with A=hi
    if (kb < 23) {
      int nb_ = (kb + 1) & 1, ko = (kb + 1) * 32;
      stageB(sm[nb_], Wlo, ko);
      if (w == 0) stageA(sm[nb_] + 6144, HcHi, ko);
    }
    computeT(kb & 1, false);
    __syncthreads();
  }

  // epilogue: lane owns (row, col) with r/z/n in acc[0..2][p]
  const int col = j0 + (w << 4) + (lane & 15);
  const int seg = (rg < 8) ? 0 : (rg == 8) ? 2 : (rg < 17) ? 1 : 3;
#pragma unroll
  for (int p = 0; p < 4; ++p) {
    const int gr = rBase + ((lane >> 4) << 2) + p;
    const float* xp; float* ho;
    if (seg == 0)      { int li = gr;       xp = xpTwf + (size_t)(s * 128 + li) * GD;        ho = TW + (size_t)(s * 128 + li) * DD + col; }
    else if (seg == 1) { int li = gr - 144; int t = 63 - s; xp = xpTwb + (size_t)(t * 128 + li) * GD; ho = TW + (size_t)(t * 128 + li) * DD + HD + col; }
    else if (seg == 2) { int li = gr - 128; xp = xpTpf + (size_t)(s * 16 + li) * GD;         ho = TP + (size_t)(s * 16 + li) * DD + col; }
    else               { int li = gr - 272; int t = 63 - s; xp = xpTpb + (size_t)(t * 16 + li) * GD;  ho = TP + (size_t)(t * 16 + li) * DD + HD + col; }
    float rv = sigmoidf_(xp[col]        + acc[0][p] + bhh[col]);
    float zv = sigmoidf_(xp[HD + col]   + acc[1][p] + bhh[HD + col]);
    float nv = tanhf    (xp[2*HD + col] + acc[2][p] + rv * (bhh[2*HD + col]) + rv * 0.f + (rv - rv));  // placeholder avoided below
    // NOTE: correct n-gate: tanh(xn + r * (hn_pre)) where hn_pre = acc[2][p] + bhh[2HD+col]
    nv = tanhf(xp[2*HD + col] + rv * (acc[2][p] + bhh[2*HD + col]));
    float hp = bf2f(HcHi[(size_t)gr * HD + col]) + bf2f(HcLo[(size_t)gr * HD + col]);
    float h = (1.f - zv) * nv + zv * hp;
    unsigned short hh = f2bf(h);
    Hn[(size_t)gr * HD + col] = hh;
    Hn[U_HLO + (size_t)gr * HD + col] = f2bf(h - bf2f(hh));
    *ho = h;
  }
}

// ---------------- TPW = TP(1024x1536) @ W_bl(1536x1536) ----------------
__global__ __launch_bounds__(256) void tpw_gemm_kernel(
    const float* __restrict__ TPm, const float* __restrict__ Wbl, float* __restrict__ TPW)
{
  __shared__ float As[16][64];
  __shared__ float Bs[16][128];
  const int tid = threadIdx.x;
  const int mBase = blockIdx.y << 6;
  const int nBase = blockIdx.x << 7;
  const int ar = tid >> 2, ak = (tid & 3) << 2;
  const int bk = tid >> 4, bn = (tid & 15) << 3;
  const float* pa = TPm + (size_t)(mBase + ar) * DD + ak;
  const float* pb = Wbl + (size_t)bk * DD + nBase + bn;
  const int tm = tid >> 4, tn = tid & 15;
  float acc[4][8];
#pragma unroll
  for (int i = 0; i < 4; ++i)
#pragma unroll
    for (int j = 0; j < 8; ++j) acc[i][j] = 0.f;

  for (int k0 = 0; k0 < DD; k0 += 16) {
    const float4 va  = *(const float4*)(pa + k0);
    const float4 vb0 = *(const float4*)(pb + (size_t)k0 * DD);
    const float4 vb1 = *(const float4*)(pb + (size_t)k0 * DD + 4);
    __syncthreads();
    As[ak+0][ar] = va.x; As[ak+1][ar] = va.y; As[ak+2][ar] = va.z; As[ak+3][ar] = va.w;
    *(float4*)&Bs[bk][bn]     = vb0;
    *(float4*)&Bs[bk][bn + 4] = vb1;
    __syncthreads();
#pragma unroll
    for (int kk = 0; kk < 16; ++kk) {
      float a[4], bb[8];
      *(float4*)&a[0] = *(const float4*)&As[kk][tm<<2];
      *(float4*)&bb[0] = *(const float4*)&Bs[kk][tn<<2];
      *(float4*)&bb[4] = *(const float4*)&Bs[kk][64 + (tn<<2)];
#pragma unroll
      for (int i = 0; i < 4; ++i)
#pragma unroll
        for (int j = 0; j < 8; ++j) acc[i][j] += a[i] * bb[j];
    }
  }
#pragma unroll
  for (int i = 0; i < 4; ++i) {
    float* po = TPW + (size_t)(mBase + (tm<<2) + i) * DD + nBase;
    *(float4*)(po + (tn<<2))      = make_float4(acc[i][0], acc[i][1], acc[i][2], acc[i][3]);
    *(float4*)(po + 64 + (tn<<2)) = make_float4(acc[i][4], acc[i][5], acc[i][6], acc[i][7]);
  }
}

// ---------------- S[b,t,l] ----------------
__global__ __launch_bounds__(128) void s_kernel(
    const float* __restrict__ TPW, const float* __restrict__ TW, float* __restrict__ S)
{
  __shared__ float tp_s[DD];
  const int t = blockIdx.x, b = blockIdx.y, tid = threadIdx.x;
  const float* src = TPW + ((size_t)b * 16 + t) * DD;
  for (int i = tid * 4; i < DD; i += 128 * 4) *(float4*)&tp_s[i] = *(const float4*)&src[i];
  __syncthreads();
  const float* twp = TW + (size_t)(b * 128 + tid) * DD;
  float acc = 0.f;
  for (int d = 0; d < DD; d += 4) {
    const float4 tv = *(const float4*)(twp + d);
    acc += tp_s[d]*tv.x + tp_s[d+1]*tv.y + tp_s[d+2]*tv.z + tp_s[d+3]*tv.w;
  }
  S[((size_t)b * 16 + t) * 128 + tid] = acc;
}

// ---------------- r = softmax(S) @ TW ----------------
__global__ __launch_bounds__(256) void r_kernel(
    const float* __restrict__ S, const float* __restrict__ TW, float* __restrict__ Rr)
{
  __shared__ float att[128];
  const int t = blockIdx.x, b = blockIdx.y, tid = threadIdx.x;
  const float* srow = S + ((size_t)b * 16 + t) * 128;
  if (tid < 128) att[tid] = srow[tid];
  __syncthreads();
  float m = -1e30f;
  for (int i = 0; i < 128; ++i) m = fmaxf(m, att[i]);
  __syncthreads();
  if (tid < 128) att[tid] = expf(att[tid] - m);
  __syncthreads();
  float ssum = 0.f;
  for (int i = 0; i < 128; ++i) ssum += att[i];
  const float inv = 1.f / ssum;

  float racc[6] = {0.f,0.f,0.f,0.f,0.f,0.f};
  const float* twb = TW + (size_t)b * 128 * DD;
  for (int l = 0; l < 128; ++l) {
    const float a = att[l];
    const float* twl = twb + (size_t)l * DD + tid;
#pragma unroll
    for (int k = 0; k < 6; ++k) racc[k] += a * twl[k * 256];
  }
  float* ro = Rr + ((size_t)b * 16 + t) * DD + tid;
#pragma unroll
  for (int k = 0; k < 6; ++k) ro[k * 256] = racc[k] * inv;
}

// ---------------- R assembly + head ----------------
__global__ __launch_bounds__(256) void final_kernel(
    const float* __restrict__ Rr, const float* __restrict__ beta,
    const float* __restrict__ detW, const float* __restrict__ detb,
    float* __restrict__ dout)
{
  __shared__ float bet[16];
  __shared__ float red0[256], red1[256];
  const int b = blockIdx.x, tid = threadIdx.x;
  if (tid < 16) bet[tid] = beta[tid];
  __syncthreads();
  const float* rb = Rr + (size_t)b * 16 * DD;
  float* Rout = dout + 128 + (size_t)b * 3072;
  float p0 = 0.f, p1 = 0.f;
  for (int d = tid; d < 3072; d += 256) {
    float v;
    if (d < DD) {
      v = rb[15 * DD + d];
    } else {
      float sum = 0.f;
#pragma unroll
      for (int tt = 0; tt < 15; ++tt) sum += bet[tt] * rb[(size_t)tt * DD + (d - DD)];
      v = sum;
    }
    Rout[d] = v;
    p0 += v * detW[d];
    p1 += v * detW[3072 + d];
  }
  red0[tid] = p0; red1[tid] = p1;
  __syncthreads();
  for (int off = 128; off > 0; off >>= 1) {
    if (tid < off) { red0[tid] += red0[tid + off]; red1[tid] += red1[tid + off]; }
    __syncthreads();
  }
  if (tid == 0) {
    dout[b * 2 + 0] = red0[0] + detb[0];
    dout[b * 2 + 1] = red1[0] + detb[1];
  }
}

// ---------------- launch ----------------
extern "C" void kernel_launch(void* const* d_in, const int* in_sizes, int n_in,
                              void* d_out, int out_size, void* d_ws, size_t ws_size,
                              hipStream_t stream)
{
  (void)in_sizes; (void)n_in; (void)out_size; (void)ws_size;
  const int*   tweet = (const int*)  d_in[0];
  const int*   topic = (const int*)  d_in[1];
  const float* beta  = (const float*)d_in[2];
  const float* emb   = (const float*)d_in[3];
  const float* Wih_f = (const float*)d_in[4];
  const float* Whh_f = (const float*)d_in[5];
  const float* bih_f = (const float*)d_in[6];
  const float* bhh_f = (const float*)d_in[7];
  const float* Wih_b = (const float*)d_in[8];
  const float* Whh_b = (const float*)d_in[9];
  const float* bih_b = (const float*)d_in[10];
  const float* bhh_b = (const float*)d_in[11];
  const float* W_bl  = (const float*)d_in[12];
  const float* det_W = (const float*)d_in[13];
  const float* det_b = (const float*)d_in[14];

  float* ws = (float*)d_ws;
  float* xp_twf = ws + F_XP_TWF;
  float* xp_twb = ws + F_XP_TWB;
  float* xp_tpf = ws + F_XP_TPF;
  float* xp_tpb = ws + F_XP_TPB;
  float* TPW    = ws + F_TPW;
  float* Sb     = ws + F_S;
  float* Rr     = ws + F_R;
  float* TW     = ws + F_TW;
  float* TPm    = ws + F_TP;
  unsigned short* uB   = reinterpret_cast<unsigned short*>(ws + F_B);
  unsigned short* uWhh = reinterpret_cast<unsigned short*>(ws + F_WHH);
  unsigned short* uH   = reinterpret_cast<unsigned short*>(ws + F_H);

  // phase 0: zero H state (pair 0: hi+lo = 221184 floats worth)
  zero_kernel<<<dim3(864), dim3(256), 0, stream>>>(ws + F_H, 221184);

  // phase 1: bf16 hi/lo splits
  gather_split_kernel<<<dim3(6144), dim3(256), 0, stream>>>(tweet, emb, uB + U_XTW_HI, uB + U_XTW_LO, 1572864);
  gather_split_kernel<<<dim3(768),  dim3(256), 0, stream>>>(topic, emb, uB + U_XTP_HI, uB + U_XTP_LO, 196608);
  split_w_kernel<<<dim3(1728), dim3(256), 0, stream>>>(Wih_f, uB + U_WIHF_HI, uB + U_WIHF_LO, 442368);
  split_w_kernel<<<dim3(1728), dim3(256), 0, stream>>>(Wih_b, uB + U_WIHB_HI, uB + U_WIHB_LO, 442368);
  split_w_kernel<<<dim3(1728), dim3(256), 0, stream>>>(Whh_f, uWhh + U_WHHF_HI, uWhh + U_WHHF_LO, 442368);
  split_w_kernel<<<dim3(1728), dim3(256), 0, stream>>>(Whh_b, uWhh + U_WHHB_HI, uWhh + U_WHHB_LO, 442368);

  // phase 2: xp GEMMs (bf16x3 MFMA)
  xp_mfma_kernel<<<dim3(1152), dim3(256), 0, stream>>>(uB + U_XTW_HI, uB + U_XTW_LO, uB + U_WIHF_HI, uB + U_WIHF_LO, bih_f, xp_twf, 64);
  xp_mfma_kernel<<<dim3(1152), dim3(256), 0, stream>>>(uB + U_XTW_HI, uB + U_XTW_LO, uB + U_WIHB_HI, uB + U_WIHB_LO, bih_b, xp_twb, 64);
  xp_mfma_kernel<<<dim3(144),  dim3(256), 0, stream>>>(uB + U_XTP_HI, uB + U_XTP_LO, uB + U_WIHF_HI, uB + U_WIHF_LO, bih_f, xp_tpf, 8);
  xp_mfma_kernel<<<dim3(144),  dim3(256), 0, stream>>>(uB + U_XTP_HI, uB + U_XTP_LO, uB + U_WIHB_HI, uB + U_WIHB_LO, bih_b, xp_tpb, 8);

  // phase 3: 64 GRU steps (writes TW/TP over the now-dead X/Wih splits)
  for (int s = 0; s < 64; ++s) {
    const unsigned short* Hc = uH + (size_t)(s & 1) * U_HPAIR;
    unsigned short*       Hn = uH + (size_t)((s & 1) ^ 1) * U_HPAIR;
    gru_mfma_kernel<<<dim3(216), dim3(256), 0, stream>>>(
        uWhh + U_WHHF_HI, uWhh + U_WHHF_LO, uWhh + U_WHHB_HI, uWhh + U_WHHB_LO,
        bhh_f, bhh_b, xp_twf, xp_twb, xp_tpf, xp_tpb, Hc, Hn, TW, TPm, s);
  }

  // phase 4: attention + head (TPW/S/R overlay the dead xp region)
  tpw_gemm_kernel<<<dim3(12, 16), dim3(256), 0, stream>>>(TPm, W_bl, TPW);
  s_kernel<<<dim3(16, 64), dim3(128), 0, stream>>>(TPW, TW, Sb);
  r_kernel<<<dim3(16, 64), dim3(256), 0, stream>>>(Sb, TW, Rr);
  final_kernel<<<dim3(64), dim3(256), 0, stream>>>(Rr, beta, det_W, det_b, (float*)d_out);
}